// Round 2
// baseline (5437.956 us; speedup 1.0000x reference)
//
#include <hip/hip_runtime.h>

// LSTM_88776974008866: bidirectional LSTM (B=2048, S=128, H=512, in=4) + 4 sigmoid heads.
// Round 2: single persistent cooperative kernel. W stationary (LDS + reg frags),
// c stationary in VGPRs, h exchanged via global with per-step grid barrier,
// XCD-local h traffic via bid mapping, swizzled A staging via global_load_lds.

typedef __attribute__((ext_vector_type(8))) __bf16 bf16x8;
typedef __attribute__((ext_vector_type(4))) float f32x4;
typedef __attribute__((ext_vector_type(8))) unsigned short u16x8;

#define NBLK 256

__device__ __forceinline__ unsigned short f2bf(float f) {
  unsigned u = __float_as_uint(f);
  u += 0x7fffu + ((u >> 16) & 1u);   // round-to-nearest-even
  return (unsigned short)(u >> 16);
}
__device__ __forceinline__ float bf2f(unsigned short s) {
  return __uint_as_float(((unsigned)s) << 16);
}
__device__ __forceinline__ float sigm(float x) { return 1.0f / (1.0f + __expf(-x)); }
__device__ __forceinline__ float tanhfast(float x) {
  float e = __expf(-2.0f * fabsf(x));
  float t = (1.0f - e) / (1.0f + e);
  return x < 0.0f ? -t : t;
}

__device__ __forceinline__ void gl_lds16(const void* g, void* l) {
  __builtin_amdgcn_global_load_lds(
      (const __attribute__((address_space(1))) unsigned int*)g,
      (__attribute__((address_space(3))) unsigned int*)l, 16, 0, 0);
}

// ---------------------------------------------------------------------------
// prep: convert Whh (fp32 [2048][512]) -> permuted bf16 Wp, plus per-row
// input-weight float4 + fused bias. Permuted row r = (j>>4)*64 + gate*16 + (j&15).
// ---------------------------------------------------------------------------
__global__ __launch_bounds__(256) void prep_k(
    const float* __restrict__ Wf_hh, const float* __restrict__ Wf_ih,
    const float* __restrict__ bf_ih, const float* __restrict__ bf_hh,
    const float* __restrict__ Wb_hh, const float* __restrict__ Wb_ih,
    const float* __restrict__ bb_ih, const float* __restrict__ bb_hh,
    unsigned short* __restrict__ Wp, float4* __restrict__ wihp,
    float* __restrict__ biasp)
{
  int flat = blockIdx.x * 256 + threadIdx.x;   // 0 .. 2*2048*64-1
  int dir = flat >> 17;
  int rem = flat & 131071;
  int r = rem >> 6;
  int c8 = rem & 63;
  const float* Whh = dir ? Wb_hh : Wf_hh;
  const float* Wih = dir ? Wb_ih : Wf_ih;
  const float* bih = dir ? bb_ih : bf_ih;
  const float* bhh = dir ? bb_hh : bf_hh;
  int j = ((r >> 6) << 4) | (r & 15);
  int gate = (r >> 4) & 3;
  int orig = gate * 512 + j;
  const float4* src = (const float4*)(Whh + (size_t)orig * 512 + c8 * 8);
  float4 a = src[0], b = src[1];
  u16x8 o;
  o[0] = f2bf(a.x); o[1] = f2bf(a.y); o[2] = f2bf(a.z); o[3] = f2bf(a.w);
  o[4] = f2bf(b.x); o[5] = f2bf(b.y); o[6] = f2bf(b.z); o[7] = f2bf(b.w);
  *(u16x8*)(Wp + ((size_t)dir << 20) + (size_t)r * 512 + c8 * 8) = o;
  if (c8 == 0) {
    wihp[(dir << 11) + r] = make_float4(Wih[orig * 4 + 0], Wih[orig * 4 + 1],
                                        Wih[orig * 4 + 2], Wih[orig * 4 + 3]);
    biasp[(dir << 11) + r] = bih[orig] + bhh[orig];
  }
}

// ---------------------------------------------------------------------------
// grid barrier: device-scope counter + generation spin.
// ---------------------------------------------------------------------------
__device__ __forceinline__ void gsync(unsigned* bar) {
  __syncthreads();
  if (threadIdx.x == 0) {
    __threadfence();
    unsigned gen = __hip_atomic_load(bar + 1, __ATOMIC_RELAXED, __HIP_MEMORY_SCOPE_AGENT);
    unsigned arrived = __hip_atomic_fetch_add(bar, 1u, __ATOMIC_ACQ_REL, __HIP_MEMORY_SCOPE_AGENT);
    if (arrived == (unsigned)(NBLK - 1)) {
      __hip_atomic_store(bar, 0u, __ATOMIC_RELAXED, __HIP_MEMORY_SCOPE_AGENT);
      __hip_atomic_store(bar + 1, gen + 1u, __ATOMIC_RELEASE, __HIP_MEMORY_SCOPE_AGENT);
    } else {
      while (__hip_atomic_load(bar + 1, __ATOMIC_ACQUIRE, __HIP_MEMORY_SCOPE_AGENT) == gen)
        __builtin_amdgcn_s_sleep(1);
    }
  }
  __syncthreads();
}

// staging: chunk [256 rows][32 k] bf16, LDS slot s holds global k-slot s^((row>>1)&3)
__device__ __forceinline__ void stage_chunk(const unsigned short* __restrict__ hin,
                                            int bm0, int k0,
                                            unsigned short* __restrict__ dstbase,
                                            int tid, int w) {
#pragma unroll
  for (int qq = 0; qq < 2; ++qq) {
    int lin = tid + qq * 512;
    int row = lin >> 2, slot = lin & 3;
    const unsigned short* src = hin + ((size_t)(bm0 + row) << 9) + k0
                              + ((slot ^ ((row >> 1) & 3)) << 3);
    gl_lds16(src, dstbase + (size_t)((w << 6) + (qq << 9)) * 8);
  }
}

__device__ __forceinline__ void read_a(const unsigned short* __restrict__ Abuf,
                                       int wm, int l15, int lhi, bf16x8 av[4]) {
#pragma unroll
  for (int mf = 0; mf < 4; ++mf) {
    int row = (wm << 6) + (mf << 4) + l15;
    av[mf] = *(const bf16x8*)&Abuf[(row << 5) + ((lhi ^ ((row >> 1) & 3)) << 3)];
  }
}

__device__ __forceinline__ void mfma16(const bf16x8 av[4], const bf16x8 bv[4],
                                       f32x4 acc[4][4]) {
#pragma unroll
  for (int mf = 0; mf < 4; ++mf)
#pragma unroll
    for (int nf = 0; nf < 4; ++nf)
      acc[mf][nf] = __builtin_amdgcn_mfma_f32_16x16x32_bf16(av[mf], bv[nf], acc[mf][nf], 0, 0, 0);
}

// ---------------------------------------------------------------------------
// Persistent kernel: 256 blocks x 512 threads, 1 block/CU, all 128 timesteps.
// Block = dir x (256 batch) x (128 permuted gate-cols = 32 j).
// bid = mi + 8*(dir*16 + ni)  => xcd(bid%8)=mi: all blocks sharing an h panel
// are on one XCD (h traffic stays in per-XCD L2).
// ---------------------------------------------------------------------------
__global__ __launch_bounds__(512, 2) void lstm_persist(
    const float* __restrict__ y,
    const unsigned short* __restrict__ Wp,
    const float4* __restrict__ wihp,
    const float* __restrict__ biasp,
    unsigned short* __restrict__ hf0, unsigned short* __restrict__ hf1,
    unsigned short* __restrict__ hb0, unsigned short* __restrict__ hb1,
    unsigned* __restrict__ bar)
{
  __shared__ alignas(16) unsigned short Wl[128 * 456];   // k<448, rows padded to 456
  __shared__ alignas(16) unsigned short As0[256 * 32];
  __shared__ alignas(16) unsigned short As1[256 * 32];

  const int tid = threadIdx.x;
  const int w = tid >> 6, lane = tid & 63;
  const int bid = blockIdx.x;
  const int mi = bid & 7;
  const int qd = bid >> 3;
  const int dir = qd >> 4;
  const int ni = qd & 15;
  const int bm0 = mi << 8;          // 256 batch rows
  const int bn0 = ni << 7;          // 128 permuted cols

  const unsigned short* W = Wp + ((size_t)dir << 20);
  const float4* wih = wihp + (dir << 11);
  const float* bias = biasp + (dir << 11);
  unsigned short* h0 = dir ? hb0 : hf0;
  unsigned short* h1 = dir ? hb1 : hf1;

  const int wm = w >> 1;            // 0..3 (64-batch quarter)
  const int wn = w & 1;             // 0..1 (64-col half)
  const int l15 = lane & 15;
  const int lhi = lane >> 4;

  // ---- one-time: W panel k<448 into LDS ----
  for (int idx = tid; idx < 128 * 56; idx += 512) {
    int row = idx / 56;
    int s8 = idx - row * 56;
    u16x8 v = *(const u16x8*)(W + ((size_t)(bn0 + row) << 9) + (s8 << 3));
    *(u16x8*)(&Wl[row * 456 + (s8 << 3)]) = v;
  }
  // ---- one-time: W k in [448,512) into register B-fragments ----
  bf16x8 bst0[4], bst1[4];
#pragma unroll
  for (int nf = 0; nf < 4; ++nf) {
    int row = bn0 + (wn << 6) + (nf << 4) + l15;
    bst0[nf] = *(const bf16x8*)(W + ((size_t)row << 9) + 448 + (lhi << 3));
    bst1[nf] = *(const bf16x8*)(W + ((size_t)row << 9) + 480 + (lhi << 3));
  }
  // per-thread input weights / fused bias (gate g = nf)
  float4 wv[4]; float bv4[4];
#pragma unroll
  for (int g = 0; g < 4; ++g) {
    int n = bn0 + (wn << 6) + (g << 4) + l15;
    wv[g] = wih[n]; bv4[g] = bias[n];
  }
  const int j = (((ni << 1) + wn) << 4) + l15;   // hidden index 0..511
  float c_reg[16];
#pragma unroll
  for (int i = 0; i < 16; ++i) c_reg[i] = 0.f;

  const float4* y4 = (const float4*)y;
  __syncthreads();   // Wl ready

#pragma unroll 1
  for (int t = 0; t < 128; ++t) {
    const unsigned short* hin = (t & 1) ? h1 : h0;
    unsigned short* hout      = (t & 1) ? h0 : h1;
    const int t_eff = dir ? (127 - t) : t;

    f32x4 acc[4][4];
#pragma unroll
    for (int a = 0; a < 4; ++a)
#pragma unroll
      for (int b = 0; b < 4; ++b) acc[a][b] = (f32x4){0.f, 0.f, 0.f, 0.f};

    stage_chunk(hin, bm0, 0, As0, tid, w);
    __syncthreads();

#pragma unroll 1
    for (int kk = 0; kk < 7; ++kk) {
      const int kt0 = kk << 1;
      // phase even: read As0, prefetch chunk kt0+1 -> As1
      stage_chunk(hin, bm0, (kt0 + 1) << 5, As1, tid, w);
      {
        bf16x8 av[4], bv[4];
        read_a(As0, wm, l15, lhi, av);
#pragma unroll
        for (int nf = 0; nf < 4; ++nf) {
          int row = (wn << 6) + (nf << 4) + l15;
          bv[nf] = *(const bf16x8*)&Wl[row * 456 + (kt0 << 5) + (lhi << 3)];
        }
        mfma16(av, bv, acc);
      }
      __syncthreads();
      // phase odd: read As1, prefetch chunk kt0+2 -> As0
      stage_chunk(hin, bm0, (kt0 + 2) << 5, As0, tid, w);
      {
        bf16x8 av[4], bv[4];
        read_a(As1, wm, l15, lhi, av);
#pragma unroll
        for (int nf = 0; nf < 4; ++nf) {
          int row = (wn << 6) + (nf << 4) + l15;
          bv[nf] = *(const bf16x8*)&Wl[row * 456 + ((kt0 + 1) << 5) + (lhi << 3)];
        }
        mfma16(av, bv, acc);
      }
      __syncthreads();
    }
    // kt=14: read As0, prefetch chunk 15 -> As1, B from regs bst0
    stage_chunk(hin, bm0, 15 << 5, As1, tid, w);
    {
      bf16x8 av[4];
      read_a(As0, wm, l15, lhi, av);
      mfma16(av, bst0, acc);
    }
    __syncthreads();
    // kt=15: read As1, B from regs bst1
    {
      bf16x8 av[4];
      read_a(As1, wm, l15, lhi, av);
      mfma16(av, bst1, acc);
    }

    // ---- epilogue: lane-local LSTM cell update, c in registers ----
#pragma unroll
    for (int mf = 0; mf < 4; ++mf) {
#pragma unroll
      for (int r = 0; r < 4; ++r) {
        const int b = bm0 + (wm << 6) + (mf << 4) + (lhi << 2) + r;
        float4 x4 = y4[(size_t)b * 128 + t_eff];
        float pre[4];
#pragma unroll
        for (int g = 0; g < 4; ++g)
          pre[g] = acc[mf][g][r] + bv4[g] + x4.x * wv[g].x + x4.y * wv[g].y
                 + x4.z * wv[g].z + x4.w * wv[g].w;
        const float ig = sigm(pre[0]);
        const float fg = sigm(pre[1]);
        const float gg = tanhfast(pre[2]);
        const float og = sigm(pre[3]);
        const float cn = fg * c_reg[mf * 4 + r] + ig * gg;
        c_reg[mf * 4 + r] = cn;
        hout[((size_t)b << 9) + j] = f2bf(og * tanhfast(cn));
      }
    }

    if (t != 127) gsync(bar);
  }
}

// ---------------------------------------------------------------------------
// heads: out[b][k] = sigmoid(hf[b]·Wk[0:512] + hb[b]·Wk[512:1024] + bk)
// ---------------------------------------------------------------------------
__global__ __launch_bounds__(256) void heads_k(
    const unsigned short* __restrict__ hf, const unsigned short* __restrict__ hb,
    const float* __restrict__ W1, const float* __restrict__ b1,
    const float* __restrict__ W2, const float* __restrict__ b2,
    const float* __restrict__ W3, const float* __restrict__ b3,
    const float* __restrict__ W4, const float* __restrict__ b4,
    float* __restrict__ out)
{
  const int wid = threadIdx.x >> 6, lane = threadIdx.x & 63;
  const int b = blockIdx.x * 4 + wid;
  const unsigned short* src = (lane < 32) ? (hf + ((size_t)b << 9) + (lane << 4))
                                          : (hb + ((size_t)b << 9) + ((lane - 32) << 4));
  const int woff = lane << 4;
  u16x8 v0 = *(const u16x8*)src;
  u16x8 v1 = *(const u16x8*)(src + 8);
  float hv[16];
#pragma unroll
  for (int e = 0; e < 8; ++e) { hv[e] = bf2f(v0[e]); hv[8 + e] = bf2f(v1[e]); }
  float s0 = 0.f, s1 = 0.f, s2 = 0.f, s3 = 0.f;
#pragma unroll
  for (int e = 0; e < 16; ++e) {
    float h = hv[e];
    s0 += h * W1[woff + e];
    s1 += h * W2[woff + e];
    s2 += h * W3[woff + e];
    s3 += h * W4[woff + e];
  }
#pragma unroll
  for (int off = 32; off >= 1; off >>= 1) {
    s0 += __shfl_xor(s0, off, 64);
    s1 += __shfl_xor(s1, off, 64);
    s2 += __shfl_xor(s2, off, 64);
    s3 += __shfl_xor(s3, off, 64);
  }
  if (lane == 0) {
    out[b * 4 + 0] = sigm(s0 + b1[0]);
    out[b * 4 + 1] = sigm(s1 + b2[0]);
    out[b * 4 + 2] = sigm(s2 + b3[0]);
    out[b * 4 + 3] = sigm(s3 + b4[0]);
  }
}

// ---------------------------------------------------------------------------
extern "C" void kernel_launch(void* const* d_in, const int* in_sizes, int n_in,
                              void* d_out, int out_size, void* d_ws, size_t ws_size,
                              hipStream_t stream) {
  (void)in_sizes; (void)n_in; (void)out_size; (void)ws_size;
  const float* y     = (const float*)d_in[0];
  const float* Wf_ih = (const float*)d_in[1];
  const float* Wf_hh = (const float*)d_in[2];
  const float* bf_ih = (const float*)d_in[3];
  const float* bf_hh = (const float*)d_in[4];
  const float* Wb_ih = (const float*)d_in[5];
  const float* Wb_hh = (const float*)d_in[6];
  const float* bb_ih = (const float*)d_in[7];
  const float* bb_hh = (const float*)d_in[8];
  const float* W1 = (const float*)d_in[9];  const float* b1 = (const float*)d_in[10];
  const float* W2 = (const float*)d_in[11]; const float* b2 = (const float*)d_in[12];
  const float* W3 = (const float*)d_in[13]; const float* b3 = (const float*)d_in[14];
  const float* W4 = (const float*)d_in[15]; const float* b4 = (const float*)d_in[16];

  char* ws = (char*)d_ws;
  const size_t MB = 1ull << 20;
  unsigned short* Wp  = (unsigned short*)(ws);            // 4MB: 2 dirs x 2MB bf16, permuted
  unsigned short* hf0 = (unsigned short*)(ws + 4 * MB);   // 2MB
  unsigned short* hb0 = (unsigned short*)(ws + 6 * MB);   // 2MB
  unsigned short* hf1 = (unsigned short*)(ws + 8 * MB);   // 2MB
  unsigned short* hb1 = (unsigned short*)(ws + 10 * MB);  // 2MB
  float4* wihp        = (float4*)(ws + 20 * MB);          // 64KB
  float* biasp        = (float*)(ws + 20 * MB + 128 * 1024); // 16KB
  unsigned* bar       = (unsigned*)(ws + 21 * MB);        // grid barrier state

  hipMemsetAsync(ws + 4 * MB, 0, 4 * MB, stream);   // hf0+hb0 = h(t=0) zeros
  hipMemsetAsync(ws + 21 * MB, 0, 256, stream);     // barrier counters

  prep_k<<<1024, 256, 0, stream>>>(Wf_hh, Wf_ih, bf_ih, bf_hh,
                                   Wb_hh, Wb_ih, bb_ih, bb_hh,
                                   Wp, wihp, biasp);

  void* args[] = { (void*)&y, (void*)&Wp, (void*)&wihp, (void*)&biasp,
                   (void*)&hf0, (void*)&hf1, (void*)&hb0, (void*)&hb1, (void*)&bar };
  hipLaunchCooperativeKernel((const void*)lstm_persist, dim3(NBLK), dim3(512),
                             args, 0, stream);

  // 128 steps (even): final h is in buffer 0 for both directions
  heads_k<<<512, 256, 0, stream>>>(hf0, hb0, W1, b1, W2, b2, W3, b3, W4, b4,
                                   (float*)d_out);
}

// Round 3
// 2879.413 us; speedup vs baseline: 1.8886x; 1.8886x over previous
//
#include <hip/hip_runtime.h>

// LSTM_88776974008866: bidirectional LSTM (B=2048, S=128, H=512, in=4) + 4 sigmoid heads.
// Round 3: persistent kernel, barrier-free K-loop. W stationary in LDS in a
// fragment-contiguous layout (conflict-free ds_read_b128, no per-step LDS writes,
// no __syncthreads in the GEMM). A-fragments read directly from global (XCD-local L2).
// Grid sync replaced by 16 independent 16-block XCD-local flag groups.

typedef __attribute__((ext_vector_type(8))) __bf16 bf16x8;
typedef __attribute__((ext_vector_type(4))) float f32x4;
typedef __attribute__((ext_vector_type(8))) unsigned short u16x8;

__device__ __forceinline__ unsigned short f2bf(float f) {
  unsigned u = __float_as_uint(f);
  u += 0x7fffu + ((u >> 16) & 1u);   // round-to-nearest-even
  return (unsigned short)(u >> 16);
}
__device__ __forceinline__ float bf2f(unsigned short s) {
  return __uint_as_float(((unsigned)s) << 16);
}
__device__ __forceinline__ float sigm(float x) { return 1.0f / (1.0f + __expf(-x)); }
__device__ __forceinline__ float tanhfast(float x) {
  float e = __expf(-2.0f * fabsf(x));
  float t = (1.0f - e) / (1.0f + e);
  return x < 0.0f ? -t : t;
}

__device__ __forceinline__ void gl_lds16(const void* g, void* l) {
  __builtin_amdgcn_global_load_lds(
      (const __attribute__((address_space(1))) unsigned int*)g,
      (__attribute__((address_space(3))) unsigned int*)l, 16, 0, 0);
}

// ---------------------------------------------------------------------------
// prep: Whh (fp32 [2048][512], gate-major rows i,f,g,o) -> Wp in the exact
// per-block fragment-contiguous LDS image:
//   chunk = ((((dir*16+ni)*2+wn)*16+kt)*4+nf)*64 + lhi*16 + l15   (16B chunks)
//   holds W[permrow = ni*128+wn*64+nf*16+l15][k = kt*32+lhi*8 .. +8)
//   where permrow corresponds to gate=nf, j=(ni*2+wn)*16+l15, orig=nf*512+j.
// Also emits wihp/biasp indexed by permuted row.
// ---------------------------------------------------------------------------
__global__ __launch_bounds__(256) void prep_k(
    const float* __restrict__ Wf_hh, const float* __restrict__ Wf_ih,
    const float* __restrict__ bf_ih, const float* __restrict__ bf_hh,
    const float* __restrict__ Wb_hh, const float* __restrict__ Wb_ih,
    const float* __restrict__ bb_ih, const float* __restrict__ bb_hh,
    unsigned short* __restrict__ Wp, float4* __restrict__ wihp,
    float* __restrict__ biasp)
{
  int flat = blockIdx.x * 256 + threadIdx.x;   // 0 .. 262143
  int l15 = flat & 15;
  int lhi = (flat >> 4) & 3;
  int nf  = (flat >> 6) & 3;
  int kt  = (flat >> 8) & 15;
  int wn  = (flat >> 12) & 1;
  int ni  = (flat >> 13) & 15;
  int dir = (flat >> 17) & 1;
  const float* Whh = dir ? Wb_hh : Wf_hh;
  const float* Wih = dir ? Wb_ih : Wf_ih;
  const float* bih = dir ? bb_ih : bf_ih;
  const float* bhh = dir ? bb_hh : bf_hh;

  int j = ((ni * 2 + wn) << 4) + l15;          // hidden index 0..511
  int orig = (nf << 9) + j;                    // original gate-major row
  int k0 = (kt << 5) + (lhi << 3);
  const float4* src = (const float4*)(Whh + (size_t)orig * 512 + k0);
  float4 a = src[0], b = src[1];
  u16x8 o;
  o[0] = f2bf(a.x); o[1] = f2bf(a.y); o[2] = f2bf(a.z); o[3] = f2bf(a.w);
  o[4] = f2bf(b.x); o[5] = f2bf(b.y); o[6] = f2bf(b.z); o[7] = f2bf(b.w);
  *(u16x8*)(Wp + (size_t)flat * 8) = o;

  if (kt == 0 && lhi == 0) {
    int rg = (ni << 7) + (wn << 6) + (nf << 4) + l15;   // permuted row
    wihp[(dir << 11) + rg] = make_float4(Wih[orig * 4 + 0], Wih[orig * 4 + 1],
                                         Wih[orig * 4 + 2], Wih[orig * 4 + 3]);
    biasp[(dir << 11) + rg] = bih[orig] + bhh[orig];
  }
}

// ---------------------------------------------------------------------------
// Persistent kernel: 256 blocks x 512 threads (1 block/CU), all 128 timesteps.
// bid = mi + 8*(dir*16 + ni): xcd = bid%8 = mi, so each (mi,dir) group of 16
// blocks (producers AND consumers of h-panel mi) is XCD-local.
// ---------------------------------------------------------------------------
__global__ __launch_bounds__(512, 2) void lstm_persist(
    const float* __restrict__ y,
    const unsigned short* __restrict__ Wp,
    const float4* __restrict__ wihp,
    const float* __restrict__ biasp,
    unsigned short* __restrict__ hf0, unsigned short* __restrict__ hf1,
    unsigned short* __restrict__ hb0, unsigned short* __restrict__ hb1,
    unsigned* __restrict__ bar)
{
  __shared__ alignas(16) unsigned short Wl[65536];   // 128 KB W image

  const int tid = threadIdx.x;
  const int w = tid >> 6, lane = tid & 63;
  const int bid = blockIdx.x;
  const int mi = bid & 7;
  const int qd = bid >> 3;
  const int dir = qd >> 4;
  const int ni = qd & 15;
  const int bm0 = mi << 8;                 // 256 batch rows

  const float4* wih = wihp + (dir << 11);
  const float* bias = biasp + (dir << 11);
  unsigned short* h0 = dir ? hb0 : hf0;
  unsigned short* h1 = dir ? hb1 : hf1;

  const int wm = w >> 1;                   // 0..3: 64-row quarter
  const int wn = w & 1;                    // 0..1: 64-col half
  const int l15 = lane & 15;
  const int lhi = lane >> 4;

  // ---- one-time: copy this block's 128KB W image into LDS (contiguous) ----
  const unsigned short* Wblk = Wp + ((size_t)((dir << 4) | ni) << 16);  // *65536 shorts
#pragma unroll
  for (int i = 0; i < 16; ++i) {
    gl_lds16(Wblk + (size_t)(((i << 9) + tid)) * 8,
             (unsigned short*)Wl + ((i << 12) + (w << 9)));
  }

  // per-thread input weights / fused bias (gate g)
  float4 wv[4]; float bv4[4];
#pragma unroll
  for (int g = 0; g < 4; ++g) {
    int n = (ni << 7) + (wn << 6) + (g << 4) + l15;
    wv[g] = wih[n]; bv4[g] = bias[n];
  }
  const int j = (((ni << 1) + wn) << 4) + l15;   // hidden index 0..511
  float c_reg[16];
#pragma unroll
  for (int i = 0; i < 16; ++i) c_reg[i] = 0.f;

  const float4* y4 = (const float4*)y;
  unsigned* flag = bar + (((dir << 3) | mi) << 6);   // 256B-spaced counters

  // LDS B-fragment base for this wave (contiguous 1KB per (kt,nf) read)
  const unsigned short* wB = Wl + (wn << 15) + (lane << 3);

  __syncthreads();   // Wl ready (syncthreads drains the global_load_lds too)

  const unsigned short* hin = h0;
  unsigned short* hout = h1;

#pragma unroll 1
  for (int t = 0; t < 128; ++t) {
    const int t_eff = dir ? (127 - t) : t;

    f32x4 acc[4][4];
#pragma unroll
    for (int a = 0; a < 4; ++a)
#pragma unroll
      for (int b = 0; b < 4; ++b) acc[a][b] = (f32x4){0.f, 0.f, 0.f, 0.f};

    // A base: row = bm0 + wm*64 + l15 (+16 per mf), k-off = lhi*8 (+32 per kt)
    const unsigned short* aB = hin + ((size_t)(bm0 + (wm << 6) + l15) << 9) + (lhi << 3);

#pragma unroll
    for (int kt = 0; kt < 16; ++kt) {
      bf16x8 a0 = *(const bf16x8*)(aB + (kt << 5));
      bf16x8 a1 = *(const bf16x8*)(aB + (16 << 9) + (kt << 5));
      bf16x8 a2 = *(const bf16x8*)(aB + (32 << 9) + (kt << 5));
      bf16x8 a3 = *(const bf16x8*)(aB + (48 << 9) + (kt << 5));
      bf16x8 b0 = *(const bf16x8*)(wB + (kt << 11));
      bf16x8 b1 = *(const bf16x8*)(wB + (kt << 11) + 512);
      bf16x8 b2 = *(const bf16x8*)(wB + (kt << 11) + 1024);
      bf16x8 b3 = *(const bf16x8*)(wB + (kt << 11) + 1536);
      acc[0][0] = __builtin_amdgcn_mfma_f32_16x16x32_bf16(a0, b0, acc[0][0], 0, 0, 0);
      acc[0][1] = __builtin_amdgcn_mfma_f32_16x16x32_bf16(a0, b1, acc[0][1], 0, 0, 0);
      acc[0][2] = __builtin_amdgcn_mfma_f32_16x16x32_bf16(a0, b2, acc[0][2], 0, 0, 0);
      acc[0][3] = __builtin_amdgcn_mfma_f32_16x16x32_bf16(a0, b3, acc[0][3], 0, 0, 0);
      acc[1][0] = __builtin_amdgcn_mfma_f32_16x16x32_bf16(a1, b0, acc[1][0], 0, 0, 0);
      acc[1][1] = __builtin_amdgcn_mfma_f32_16x16x32_bf16(a1, b1, acc[1][1], 0, 0, 0);
      acc[1][2] = __builtin_amdgcn_mfma_f32_16x16x32_bf16(a1, b2, acc[1][2], 0, 0, 0);
      acc[1][3] = __builtin_amdgcn_mfma_f32_16x16x32_bf16(a1, b3, acc[1][3], 0, 0, 0);
      acc[2][0] = __builtin_amdgcn_mfma_f32_16x16x32_bf16(a2, b0, acc[2][0], 0, 0, 0);
      acc[2][1] = __builtin_amdgcn_mfma_f32_16x16x32_bf16(a2, b1, acc[2][1], 0, 0, 0);
      acc[2][2] = __builtin_amdgcn_mfma_f32_16x16x32_bf16(a2, b2, acc[2][2], 0, 0, 0);
      acc[2][3] = __builtin_amdgcn_mfma_f32_16x16x32_bf16(a2, b3, acc[2][3], 0, 0, 0);
      acc[3][0] = __builtin_amdgcn_mfma_f32_16x16x32_bf16(a3, b0, acc[3][0], 0, 0, 0);
      acc[3][1] = __builtin_amdgcn_mfma_f32_16x16x32_bf16(a3, b1, acc[3][1], 0, 0, 0);
      acc[3][2] = __builtin_amdgcn_mfma_f32_16x16x32_bf16(a3, b2, acc[3][2], 0, 0, 0);
      acc[3][3] = __builtin_amdgcn_mfma_f32_16x16x32_bf16(a3, b3, acc[3][3], 0, 0, 0);
    }

    // ---- epilogue: lane-local LSTM cell update, c in registers ----
#pragma unroll
    for (int mf = 0; mf < 4; ++mf) {
#pragma unroll
      for (int r = 0; r < 4; ++r) {
        const int b = bm0 + (wm << 6) + (mf << 4) + (lhi << 2) + r;
        float4 x4 = y4[(size_t)b * 128 + t_eff];
        float pre[4];
#pragma unroll
        for (int g = 0; g < 4; ++g)
          pre[g] = acc[mf][g][r] + bv4[g] + x4.x * wv[g].x + x4.y * wv[g].y
                 + x4.z * wv[g].z + x4.w * wv[g].w;
        const float ig = sigm(pre[0]);
        const float fg = sigm(pre[1]);
        const float gg = tanhfast(pre[2]);
        const float og = sigm(pre[3]);
        const float cn = fg * c_reg[mf * 4 + r] + ig * gg;
        c_reg[mf * 4 + r] = cn;
        hout[((size_t)b << 9) + j] = f2bf(og * tanhfast(cn));
      }
    }

    // ---- XCD-local group handshake (16 blocks sharing (mi,dir)) ----
    if (t != 127) {
      __syncthreads();   // drains all waves' stores (vmcnt(0) before s_barrier)
      if (tid == 0) {
        __hip_atomic_fetch_add(flag, 1u, __ATOMIC_RELAXED, __HIP_MEMORY_SCOPE_AGENT);
        const unsigned tgt = 16u * (unsigned)(t + 1);
        while (__hip_atomic_load(flag, __ATOMIC_RELAXED, __HIP_MEMORY_SCOPE_AGENT) < tgt)
          __builtin_amdgcn_s_sleep(1);
        // one acquire: L1 invalidate so next step's h reads are fresh
        (void)__hip_atomic_load(flag, __ATOMIC_ACQUIRE, __HIP_MEMORY_SCOPE_AGENT);
      }
      __syncthreads();
    }

    // swap h buffers
    const unsigned short* tmp = hin; hin = hout; hout = (unsigned short*)tmp;
  }
}

// ---------------------------------------------------------------------------
// heads: out[b][k] = sigmoid(hf[b]·Wk[0:512] + hb[b]·Wk[512:1024] + bk)
// ---------------------------------------------------------------------------
__global__ __launch_bounds__(256) void heads_k(
    const unsigned short* __restrict__ hf, const unsigned short* __restrict__ hb,
    const float* __restrict__ W1, const float* __restrict__ b1,
    const float* __restrict__ W2, const float* __restrict__ b2,
    const float* __restrict__ W3, const float* __restrict__ b3,
    const float* __restrict__ W4, const float* __restrict__ b4,
    float* __restrict__ out)
{
  const int wid = threadIdx.x >> 6, lane = threadIdx.x & 63;
  const int b = blockIdx.x * 4 + wid;
  const unsigned short* src = (lane < 32) ? (hf + ((size_t)b << 9) + (lane << 4))
                                          : (hb + ((size_t)b << 9) + ((lane - 32) << 4));
  const int woff = lane << 4;
  u16x8 v0 = *(const u16x8*)src;
  u16x8 v1 = *(const u16x8*)(src + 8);
  float hv[16];
#pragma unroll
  for (int e = 0; e < 8; ++e) { hv[e] = bf2f(v0[e]); hv[8 + e] = bf2f(v1[e]); }
  float s0 = 0.f, s1 = 0.f, s2 = 0.f, s3 = 0.f;
#pragma unroll
  for (int e = 0; e < 16; ++e) {
    float h = hv[e];
    s0 += h * W1[woff + e];
    s1 += h * W2[woff + e];
    s2 += h * W3[woff + e];
    s3 += h * W4[woff + e];
  }
#pragma unroll
  for (int off = 32; off >= 1; off >>= 1) {
    s0 += __shfl_xor(s0, off, 64);
    s1 += __shfl_xor(s1, off, 64);
    s2 += __shfl_xor(s2, off, 64);
    s3 += __shfl_xor(s3, off, 64);
  }
  if (lane == 0) {
    out[b * 4 + 0] = sigm(s0 + b1[0]);
    out[b * 4 + 1] = sigm(s1 + b2[0]);
    out[b * 4 + 2] = sigm(s2 + b3[0]);
    out[b * 4 + 3] = sigm(s3 + b4[0]);
  }
}

// ---------------------------------------------------------------------------
extern "C" void kernel_launch(void* const* d_in, const int* in_sizes, int n_in,
                              void* d_out, int out_size, void* d_ws, size_t ws_size,
                              hipStream_t stream) {
  (void)in_sizes; (void)n_in; (void)out_size; (void)ws_size;
  const float* y     = (const float*)d_in[0];
  const float* Wf_ih = (const float*)d_in[1];
  const float* Wf_hh = (const float*)d_in[2];
  const float* bf_ih = (const float*)d_in[3];
  const float* bf_hh = (const float*)d_in[4];
  const float* Wb_ih = (const float*)d_in[5];
  const float* Wb_hh = (const float*)d_in[6];
  const float* bb_ih = (const float*)d_in[7];
  const float* bb_hh = (const float*)d_in[8];
  const float* W1 = (const float*)d_in[9];  const float* b1 = (const float*)d_in[10];
  const float* W2 = (const float*)d_in[11]; const float* b2 = (const float*)d_in[12];
  const float* W3 = (const float*)d_in[13]; const float* b3 = (const float*)d_in[14];
  const float* W4 = (const float*)d_in[15]; const float* b4 = (const float*)d_in[16];

  char* ws = (char*)d_ws;
  const size_t MB = 1ull << 20;
  unsigned short* Wp  = (unsigned short*)(ws);            // 4MB: per-block LDS images
  unsigned short* hf0 = (unsigned short*)(ws + 4 * MB);   // 2MB
  unsigned short* hb0 = (unsigned short*)(ws + 6 * MB);   // 2MB
  unsigned short* hf1 = (unsigned short*)(ws + 8 * MB);   // 2MB
  unsigned short* hb1 = (unsigned short*)(ws + 10 * MB);  // 2MB
  float4* wihp        = (float4*)(ws + 20 * MB);          // 64KB
  float* biasp        = (float*)(ws + 20 * MB + 128 * 1024); // 16KB
  unsigned* bar       = (unsigned*)(ws + 21 * MB);        // 16 flag counters, 256B apart

  hipMemsetAsync(ws + 4 * MB, 0, 4 * MB, stream);   // hf0+hb0 = h(t=0) zeros
  hipMemsetAsync(ws + 21 * MB, 0, 4096, stream);    // flag counters

  prep_k<<<1024, 256, 0, stream>>>(Wf_hh, Wf_ih, bf_ih, bf_hh,
                                   Wb_hh, Wb_ih, bb_ih, bb_hh,
                                   Wp, wihp, biasp);

  void* args[] = { (void*)&y, (void*)&Wp, (void*)&wihp, (void*)&biasp,
                   (void*)&hf0, (void*)&hf1, (void*)&hb0, (void*)&hb1, (void*)&bar };
  hipLaunchCooperativeKernel((const void*)lstm_persist, dim3(256), dim3(512),
                             args, 0, stream);

  // 128 steps (even): final h is in buffer 0 for both directions
  heads_k<<<512, 256, 0, stream>>>(hf0, hb0, W1, b1, W2, b2, W3, b3, W4, b4,
                                   (float*)d_out);
}